// Round 16
// baseline (691.486 us; speedup 1.0000x reference)
//
#include <hip/hip_runtime.h>

// 3-layer LSTM, B=256, T=2048, H=32, in=64. fp32.
// r15 structure (6 waves, producer/consumer, 16-step chunks, exp2-domain
// pre-scaled weights). Round-16 change: software-pipeline the h-broadcast
// into the next step's dot (readlane -> pk_fma fused, no serial 32-readlane
// block on the chain) + keep c in 2*log2e-scaled domain + single-fma
// activation tails with precomputed per-lane constants.
//   w3: f0 (chunk p) | w0: rec0 (p-1) | w4: f1 (p-2) | w1: rec1 (p-3)
//   w5: f2 (p-4)     | w2: rec2+proj (p-5)

typedef float v2f __attribute__((ext_vector_type(2)));

constexpr int T_SEQ  = 2048;
constexpr int CH     = 16;
constexpr int NCHUNK = T_SEQ / CH;     // 128
constexpr int NPHASE = NCHUNK + 5;
constexpr float LOG2E  = 1.44269504088896f;
constexpr float TWOL2E = 2.88539008177793f;   // 2*log2(e)

#define GLOAD_LDS16(gsrc, ldst)                                                              \
    __builtin_amdgcn_global_load_lds((const __attribute__((address_space(1))) void*)(gsrc), \
                                     (__attribute__((address_space(3))) void*)(ldst),        \
                                     16, 0, 0)
#define KEEPV(x) asm volatile("" : "+v"(x))

__device__ __forceinline__ float rcp_f(float x) { return __builtin_amdgcn_rcpf(x); }
__device__ __forceinline__ float exp2_f(float x) { return __builtin_amdgcn_exp2f(x); }

// returns x[l] + x[l^32] for every lane, via one permlane32_swap (VALU).
__device__ __forceinline__ float swap_sum32(float x) {
#if __has_builtin(__builtin_amdgcn_permlane32_swap)
    auto r = __builtin_amdgcn_permlane32_swap(__float_as_uint(x), __float_as_uint(x),
                                              false, false);
    return __uint_as_float(r[0]) + __uint_as_float(r[1]);
#else
    return x + __shfl_xor(x, 32);
#endif
}

// One chunk of recurrence, software-pipelined:
//   dot(0) from persisted hs; per step: acts -> z -> {fused readlane+dot(t+1)}
// Lane l owns gate rows l (A) and l+64 (B): l<32 -> A=i, B=g; l>=32 -> A=f, B=o.
// Pre-activations PRE-SCALED: A rows by -log2e; B rows by TWOL2E (l<32) /
// LOG2E (l>=32). c is kept in the TWOL2E-scaled domain (CA2/CAB fold).
// z: lanes>=32 hold h_new after each step. hs[32] persists across chunks.
template<bool RING>
__device__ __forceinline__ void rec_chunk(int l,
    const v2f* __restrict__ xg_in,        // [CH][64] scaled gate pre-activations
    float* __restrict__ ring_out,         // [CH][32] h chunk to next feeder
    const v2f (&whA)[16], const v2f (&whB)[16],   // pre-scaled
    float (&hs)[32], float& c, float& z,
    float CA2, float CAB)
{
    // prefetch the whole chunk's xg into registers (one lgkm batch)
    v2f xgr[CH];
#pragma unroll
    for (int tt = 0; tt < CH; ++tt) xgr[tt] = xg_in[tt * 64 + l];

    // dot for step 0 from persisted hs
    v2f aA0 = {xgr[0].x, 0.f}, aA1 = {0.f, 0.f};
    v2f aB0 = {xgr[0].y, 0.f}, aB1 = {0.f, 0.f};
#pragma unroll
    for (int j = 0; j < 16; j += 2) {
        const v2f h0 = {hs[2*j],     hs[2*j + 1]};
        const v2f h1 = {hs[2*j + 2], hs[2*j + 3]};
        aA0 = h0 * whA[j]     + aA0;  aB0 = h0 * whB[j]     + aB0;
        aA1 = h1 * whA[j + 1] + aA1;  aB1 = h1 * whB[j + 1] + aB1;
    }

#pragma unroll
    for (int tt = 0; tt < CH; ++tt) {
        const float ga = (aA0.x + aA1.x) + (aA0.y + aA1.y);
        const float gb = (aB0.x + aB1.x) + (aB0.y + aB1.y);

        const float sA   = rcp_f(1.0f + exp2_f(ga));      // i | f
        const float r1   = rcp_f(exp2_f(gb) + 1.0f);
        const float vB   = fmaf(CA2, r1, CAB);            // TWOL2E*g | o
        const float m2vB = -2.0f * vB;                    // off-chain

        const float p  = sA * ((l < 32) ? vB : c);        // TWOL2E*i*g | f*c'
        const float cn = swap_sum32(p);                   // scaled c_new
        const float r2 = rcp_f(exp2_f(cn) + 1.0f);        // no pre-mul: cn scaled
        z = fmaf(m2vB, r2, vB);                           // lanes>=32: h_new
        c = cn;

        if constexpr (RING) { if (l >= 32) ring_out[tt * 32 + (l - 32)] = z; }

        const int zb = __float_as_int(z);
        if (tt + 1 < CH) {
            // fused broadcast + next-step dot: readlane pairs feed pk_fma
            aA0 = (v2f){xgr[tt + 1].x, 0.f}; aA1 = (v2f){0.f, 0.f};
            aB0 = (v2f){xgr[tt + 1].y, 0.f}; aB1 = (v2f){0.f, 0.f};
#pragma unroll
            for (int j = 0; j < 16; j += 2) {
                const float h00 = __int_as_float(__builtin_amdgcn_readlane(zb, 2*j + 32));
                const float h01 = __int_as_float(__builtin_amdgcn_readlane(zb, 2*j + 33));
                const v2f h0 = {h00, h01};
                aA0 = h0 * whA[j] + aA0;  aB0 = h0 * whB[j] + aB0;
                const float h10 = __int_as_float(__builtin_amdgcn_readlane(zb, 2*j + 34));
                const float h11 = __int_as_float(__builtin_amdgcn_readlane(zb, 2*j + 35));
                const v2f h1 = {h10, h11};
                aA1 = h1 * whA[j + 1] + aA1;  aB1 = h1 * whB[j + 1] + aB1;
            }
        } else {
            // chunk epilogue: persist broadcast for next chunk's step-0 dot
#pragma unroll
            for (int k = 0; k < 32; ++k)
                hs[k] = __int_as_float(__builtin_amdgcn_readlane(zb, k + 32));
        }
    }
}

// feeder from 32-wide LDS h ring; weights pre-scaled
__device__ __forceinline__ void feed_h_chunk(int l, const float* __restrict__ hr,
    v2f* __restrict__ xg_out, const v2f (&wA)[16], const v2f (&wB)[16],
    float bA, float bB)
{
#pragma unroll
    for (int tt = 0; tt < CH; ++tt) {
        const float4* h4 = reinterpret_cast<const float4*>(hr + tt * 32);
        v2f a0 = {bA, 0.f}, a1 = {0.f, 0.f}, b0 = {bB, 0.f}, b1 = {0.f, 0.f};
#pragma unroll
        for (int i = 0; i < 8; ++i) {
            const float4 v = h4[i];
            const v2f lo = {v.x, v.y}, hi = {v.z, v.w};
            a0 = lo * wA[2*i] + a0;  a1 = hi * wA[2*i+1] + a1;
            b0 = lo * wB[2*i] + b0;  b1 = hi * wB[2*i+1] + b1;
        }
        xg_out[tt * 64 + l] = (v2f){(a0.x + a1.x) + (a0.y + a1.y),
                                    (b0.x + b1.x) + (b0.y + b1.y)};
    }
}

// feeder layer 0 from staged x (64-wide rows); weights pre-scaled
__device__ __forceinline__ void feed0_chunk(int l, const float* __restrict__ xs,
    v2f* __restrict__ xg_out, const v2f (&wA)[32], const v2f (&wB)[32],
    float bA, float bB)
{
#pragma unroll
    for (int tt = 0; tt < CH; ++tt) {
        const float4* xt = reinterpret_cast<const float4*>(xs + tt * 64);
        v2f a0 = {bA, 0.f}, a1 = {0.f, 0.f}, b0 = {bB, 0.f}, b1 = {0.f, 0.f};
#pragma unroll
        for (int i = 0; i < 16; ++i) {
            const float4 v = xt[i];
            const v2f lo = {v.x, v.y}, hi = {v.z, v.w};
            a0 = lo * wA[2*i] + a0;  a1 = hi * wA[2*i+1] + a1;
            b0 = lo * wB[2*i] + b0;  b1 = hi * wB[2*i+1] + b1;
        }
        xg_out[tt * 64 + l] = (v2f){(a0.x + a1.x) + (a0.y + a1.y),
                                    (b0.x + b1.x) + (b0.y + b1.y)};
    }
}

__global__ __launch_bounds__(384) __attribute__((amdgpu_waves_per_eu(2, 2)))
void lstm3_sp_kernel(const float* __restrict__ x,
    const float* __restrict__ W_ih0, const float* __restrict__ W_hh0, const float* __restrict__ b0,
    const float* __restrict__ W_ih1, const float* __restrict__ W_hh1, const float* __restrict__ b1,
    const float* __restrict__ W_ih2, const float* __restrict__ W_hh2, const float* __restrict__ b2,
    const float* __restrict__ W_out, const float* __restrict__ b_out,
    float* __restrict__ out)
{
    const int bi = blockIdx.x;
    const int w  = threadIdx.x >> 6;
    const int l  = threadIdx.x & 63;

    __shared__ v2f   xg0[2][CH][64];       // 16 KB (scaled pre-acts)
    __shared__ v2f   xg1[2][CH][64];       // 16 KB
    __shared__ v2f   xg2[2][CH][64];       // 16 KB
    __shared__ float h0r[2][CH][32];       // 4 KB
    __shared__ float h1r[2][CH][32];       // 4 KB
    __shared__ float xstage[2][CH * 64];   // 8 KB

    // per-lane scale/act constants (exp -> exp2 domain fold; c kept scaled)
    const float sclA = -LOG2E;                               // i | f rows
    const float sclB = (l < 32) ? TWOL2E : LOG2E;            // g | o rows
    const float CA2  = (l < 32) ? -2.0f * TWOL2E : -1.0f;    // -2*ca
    const float CAB  = (l < 32) ? TWOL2E : 1.0f;             // ca + cb

    if (w == 0) {                          // ---- rec0 (chunk p-1) [SIMD0] ----
        __builtin_amdgcn_s_setprio(1);
        v2f whA[16], whB[16];
        const v2f* hA = reinterpret_cast<const v2f*>(W_hh0 + l * 32);
        const v2f* hB = reinterpret_cast<const v2f*>(W_hh0 + (l + 64) * 32);
#pragma unroll
        for (int i = 0; i < 16; ++i) {
            whA[i] = hA[i] * (v2f){sclA, sclA}; KEEPV(whA[i]);
            whB[i] = hB[i] * (v2f){sclB, sclB}; KEEPV(whB[i]);
        }
        float hs[32];
#pragma unroll
        for (int k = 0; k < 32; ++k) hs[k] = 0.f;
        float c = 0.f, z = 0.f;
        __syncthreads();
        for (int p = 0; p < NPHASE; ++p) {
            const int ci = p - 1;
            if (ci >= 0 && ci < NCHUNK)
                rec_chunk<true>(l, &xg0[ci & 1][0][0], &h0r[ci & 1][0][0],
                                whA, whB, hs, c, z, CA2, CAB);
            __syncthreads();
        }
    } else if (w == 1) {                   // ---- rec1 (chunk p-3) [SIMD1] ----
        __builtin_amdgcn_s_setprio(1);
        v2f whA[16], whB[16];
        const v2f* hA = reinterpret_cast<const v2f*>(W_hh1 + l * 32);
        const v2f* hB = reinterpret_cast<const v2f*>(W_hh1 + (l + 64) * 32);
#pragma unroll
        for (int i = 0; i < 16; ++i) {
            whA[i] = hA[i] * (v2f){sclA, sclA}; KEEPV(whA[i]);
            whB[i] = hB[i] * (v2f){sclB, sclB}; KEEPV(whB[i]);
        }
        float hs[32];
#pragma unroll
        for (int k = 0; k < 32; ++k) hs[k] = 0.f;
        float c = 0.f, z = 0.f;
        __syncthreads();
        for (int p = 0; p < NPHASE; ++p) {
            const int ci = p - 3;
            if (ci >= 0 && ci < NCHUNK)
                rec_chunk<true>(l, &xg1[ci & 1][0][0], &h1r[ci & 1][0][0],
                                whA, whB, hs, c, z, CA2, CAB);
            __syncthreads();
        }
    } else if (w == 2) {                   // ---- rec2 (chunk p-5) + proj [SIMD2] ----
        __builtin_amdgcn_s_setprio(1);
        v2f whA[16], whB[16];
        const v2f* hA = reinterpret_cast<const v2f*>(W_hh2 + l * 32);
        const v2f* hB = reinterpret_cast<const v2f*>(W_hh2 + (l + 64) * 32);
#pragma unroll
        for (int i = 0; i < 16; ++i) {
            whA[i] = hA[i] * (v2f){sclA, sclA}; KEEPV(whA[i]);
            whB[i] = hB[i] * (v2f){sclB, sclB}; KEEPV(whB[i]);
        }
        const float woutv = W_out[l & 31];
        float hs[32];
#pragma unroll
        for (int k = 0; k < 32; ++k) hs[k] = 0.f;
        float c = 0.f, z = 0.f;
        __syncthreads();
        for (int p = 0; p < NPHASE; ++p) {
            const int ci = p - 5;
            if (ci >= 0 && ci < NCHUNK)
                rec_chunk<false>(l, &xg2[ci & 1][0][0], nullptr,
                                 whA, whB, hs, c, z, CA2, CAB);
            __syncthreads();
        }
        // h2[T-1] lives in lanes 32..63
        float s = (l >= 32) ? z * woutv : 0.f;
#pragma unroll
        for (int off = 32; off; off >>= 1) s += __shfl_xor(s, off);
        if (l == 0) out[bi] = s + b_out[0];
    } else if (w == 3) {                   // ---- f0: xg0 from x (chunk p) [SIMD3] ----
        v2f wA[32], wB[32];
        const v2f* pA = reinterpret_cast<const v2f*>(W_ih0 + l * 64);
        const v2f* pB = reinterpret_cast<const v2f*>(W_ih0 + (l + 64) * 64);
#pragma unroll
        for (int i = 0; i < 32; ++i) {
            wA[i] = pA[i] * (v2f){sclA, sclA}; KEEPV(wA[i]);
            wB[i] = pB[i] * (v2f){sclB, sclB}; KEEPV(wB[i]);
        }
        const float bAv = b0[l] * sclA, bBv = b0[l + 64] * sclB;
        const float* src = x + (size_t)bi * T_SEQ * 64;
#pragma unroll
        for (int i = 0; i < 4; ++i)
            GLOAD_LDS16(src + i * 256 + l * 4, &xstage[0][i * 256 + l * 4]);
        __syncthreads();                   // drains vmcnt -> chunk 0 resident
        for (int p = 0; p < NPHASE; ++p) {
            if (p + 1 < NCHUNK) {          // prefetch next chunk
                const float* ns = src + (size_t)(p + 1) * CH * 64;
                float* dst = &xstage[(p + 1) & 1][0];
#pragma unroll
                for (int i = 0; i < 4; ++i)
                    GLOAD_LDS16(ns + i * 256 + l * 4, dst + i * 256 + l * 4);
            }
            if (p < NCHUNK)
                feed0_chunk(l, xstage[p & 1], &xg0[p & 1][0][0], wA, wB, bAv, bBv);
            __syncthreads();
        }
    } else if (w == 4) {                   // ---- f1: xg1 from h0 ring (chunk p-2) [SIMD0] ----
        v2f wA[16], wB[16];
        const v2f* pA = reinterpret_cast<const v2f*>(W_ih1 + l * 32);
        const v2f* pB = reinterpret_cast<const v2f*>(W_ih1 + (l + 64) * 32);
#pragma unroll
        for (int i = 0; i < 16; ++i) {
            wA[i] = pA[i] * (v2f){sclA, sclA}; KEEPV(wA[i]);
            wB[i] = pB[i] * (v2f){sclB, sclB}; KEEPV(wB[i]);
        }
        const float bAv = b1[l] * sclA, bBv = b1[l + 64] * sclB;
        __syncthreads();
        for (int p = 0; p < NPHASE; ++p) {
            const int ci = p - 2;
            if (ci >= 0 && ci < NCHUNK)
                feed_h_chunk(l, &h0r[ci & 1][0][0], &xg1[ci & 1][0][0], wA, wB, bAv, bBv);
            __syncthreads();
        }
    } else {                               // ---- f2: xg2 from h1 ring (chunk p-4) [SIMD1] ----
        v2f wA[16], wB[16];
        const v2f* pA = reinterpret_cast<const v2f*>(W_ih2 + l * 32);
        const v2f* pB = reinterpret_cast<const v2f*>(W_ih2 + (l + 64) * 32);
#pragma unroll
        for (int i = 0; i < 16; ++i) {
            wA[i] = pA[i] * (v2f){sclA, sclA}; KEEPV(wA[i]);
            wB[i] = pB[i] * (v2f){sclB, sclB}; KEEPV(wB[i]);
        }
        const float bAv = b2[l] * sclA, bBv = b2[l + 64] * sclB;
        __syncthreads();
        for (int p = 0; p < NPHASE; ++p) {
            const int ci = p - 4;
            if (ci >= 0 && ci < NCHUNK)
                feed_h_chunk(l, &h1r[ci & 1][0][0], &xg2[ci & 1][0][0], wA, wB, bAv, bBv);
            __syncthreads();
        }
    }
}

extern "C" void kernel_launch(void* const* d_in, const int* in_sizes, int n_in,
                              void* d_out, int out_size, void* d_ws, size_t ws_size,
                              hipStream_t stream) {
    const float* x      = (const float*)d_in[0];
    const float* W_ih0  = (const float*)d_in[1];
    const float* W_hh0  = (const float*)d_in[2];
    const float* b0     = (const float*)d_in[3];
    const float* W_ih1  = (const float*)d_in[4];
    const float* W_hh1  = (const float*)d_in[5];
    const float* b1     = (const float*)d_in[6];
    const float* W_ih2  = (const float*)d_in[7];
    const float* W_hh2  = (const float*)d_in[8];
    const float* b2     = (const float*)d_in[9];
    const float* W_out  = (const float*)d_in[10];
    const float* b_out  = (const float*)d_in[11];

    lstm3_sp_kernel<<<256, 384, 0, stream>>>(x,
                                             W_ih0, W_hh0, b0,
                                             W_ih1, W_hh1, b1,
                                             W_ih2, W_hh2, b2,
                                             W_out, b_out,
                                             (float*)d_out);
}